// Round 6
// baseline (1301.937 us; speedup 1.0000x reference)
//
#include <hip/hip_runtime.h>
#include <stdint.h>

typedef __attribute__((ext_vector_type(4))) float f32x4;
typedef __attribute__((ext_vector_type(8))) _Float16 f16x8;

static __device__ __forceinline__ unsigned short f2h(float f) {
    union { _Float16 h; unsigned short u; } v;
    v.h = (_Float16)f;                      // v_cvt_f16_f32, RNE
    return v.u;
}
static __device__ __forceinline__ float h2f_lo(unsigned int u) {
    union { unsigned short s; _Float16 h; } v; v.s = (unsigned short)(u & 0xffffu);
    return (float)v.h;
}
static __device__ __forceinline__ float h2f_hi(unsigned int u) {
    union { unsigned short s; _Float16 h; } v; v.s = (unsigned short)(u >> 16);
    return (float)v.h;
}
static __device__ __forceinline__ f16x8 as_f16x8(uint4 v) {
    union { uint4 u; f16x8 s; } x; x.u = v; return x.s;
}
static __device__ __forceinline__ float sigmoid_fast(float x) {
    return __builtin_amdgcn_rcpf(1.0f + __builtin_amdgcn_exp2f(-1.4426950408889634f * x));
}
static __device__ __forceinline__ float tanh_fast(float x) {
    return 1.0f - 2.0f * __builtin_amdgcn_rcpf(1.0f + __builtin_amdgcn_exp2f(2.8853900817779268f * x));
}
// barrier that waits only LDS (lgkmcnt(0)), NOT vmcnt — global stores keep retiring async.
static __device__ __forceinline__ void lds_barrier() {
    __builtin_amdgcn_s_waitcnt(0xc07f);
    __builtin_amdgcn_s_barrier();
}

// ---------- fused fp32 -> fp16 conversion for all 6 tensors (1 dispatch) ----------
__global__ __launch_bounds__(256) void convert_all(
    const float* __restrict__ h, const float* __restrict__ c,
    const float* __restrict__ iWh, const float* __restrict__ iWc,
    const float* __restrict__ Wih, const float* __restrict__ Whh,
    unsigned short* __restrict__ hc_h, unsigned short* __restrict__ iWh_h,
    unsigned short* __restrict__ iWc_h, unsigned short* __restrict__ Wih_h,
    unsigned short* __restrict__ Whh_h) {
    int i = blockIdx.x * 256 + threadIdx.x;      // float4 index, total 589824
    const float* src; unsigned short* dst;
    if (i < 131072) {            // h -> hc[:, 0:512]
        int base = i * 4, r = base >> 9, cc = base & 511;
        src = h + base; dst = hc_h + r * 1024 + cc;
    } else if (i < 262144) {     // c -> hc[:, 512:1024]
        int j = i - 131072; int base = j * 4, r = base >> 9, cc = base & 511;
        src = c + base; dst = hc_h + r * 1024 + 512 + cc;
    } else if (i < 327680) { int j = i - 262144; src = iWh + j * 4; dst = iWh_h + j * 4; }
    else if (i < 393216)   { int j = i - 327680; src = iWc + j * 4; dst = iWc_h + j * 4; }
    else if (i < 524288)   { int j = i - 393216; src = Wih + j * 4; dst = Wih_h + j * 4; }
    else                   { int j = i - 524288; src = Whh + j * 4; dst = Whh_h + j * 4; }
    float4 v = *(const float4*)src;
    dst[0] = f2h(v.x); dst[1] = f2h(v.y); dst[2] = f2h(v.z); dst[3] = f2h(v.w);
}

// ---------- generic C[M,N] = A[M,lda] @ W[N,ldw(:K)]^T + bias (+ELU), fp16 in / fp32 out ----
__global__ __launch_bounds__(256) void gemm_bt(
    const unsigned short* __restrict__ A, const unsigned short* __restrict__ W,
    float* __restrict__ C, const float* __restrict__ b1, const float* __restrict__ b2,
    int K, int lda, int ldw, int N, int do_elu, int bias_row) {
    __shared__ unsigned short As[64][40];
    __shared__ unsigned short Bs[64][40];
    int tid = threadIdx.x;
    int lane = tid & 63, wv = tid >> 6;
    int q = lane >> 4, l15 = lane & 15;
    int Mbase = blockIdx.x * 64, Nbase = blockIdx.y * 64;
    int ldrow = tid >> 2, seg = tid & 3;
    const unsigned short* Ap = A + (size_t)(Mbase + ldrow) * lda + seg * 8;
    const unsigned short* Wp = W + (size_t)(Nbase + ldrow) * ldw + seg * 8;
    f32x4 acc[4] = {};
    for (int k0 = 0; k0 < K; k0 += 32) {
        uint4 av = *(const uint4*)(Ap + k0);
        uint4 wvv = *(const uint4*)(Wp + k0);
        __syncthreads();
        *(uint4*)(&As[ldrow][seg * 8]) = av;
        *(uint4*)(&Bs[ldrow][seg * 8]) = wvv;
        __syncthreads();
        f16x8 af = *(const f16x8*)(&As[wv * 16 + l15][q * 8]);
#pragma unroll
        for (int nt = 0; nt < 4; nt++) {
            f16x8 bf = *(const f16x8*)(&Bs[nt * 16 + l15][q * 8]);
            acc[nt] = __builtin_amdgcn_mfma_f32_16x16x32_f16(af, bf, acc[nt], 0, 0, 0);
        }
    }
#pragma unroll
    for (int nt = 0; nt < 4; nt++) {
        int col = Nbase + nt * 16 + l15;
        float bcol = bias_row ? 0.0f : (b1[col] + (b2 ? b2[col] : 0.0f));
#pragma unroll
        for (int r = 0; r < 4; r++) {
            int row = Mbase + wv * 16 + q * 4 + r;
            float bias = bias_row ? (b1[row] + (b2 ? b2[row] : 0.0f)) : bcol;
            float v = acc[nt][r] + bias;
            if (do_elu) v = v > 0.0f ? v : (__builtin_amdgcn_exp2f(1.4426950408889634f * v) - 1.0f);
            C[(size_t)row * N + col] = v;
        }
    }
}

// ---------- fused init-state GEMMs (h0 and c0 via blockIdx.z), K=1024, N=256, ELU ----------
__global__ __launch_bounds__(256) void gemm_init(
    const unsigned short* __restrict__ A,
    const unsigned short* __restrict__ W0, const unsigned short* __restrict__ W1,
    float* __restrict__ C0, float* __restrict__ C1,
    const float* __restrict__ bias0, const float* __restrict__ bias1) {
    const unsigned short* W = blockIdx.z ? W1 : W0;
    float* C = blockIdx.z ? C1 : C0;
    const float* bias = blockIdx.z ? bias1 : bias0;
    __shared__ unsigned short As[64][40];
    __shared__ unsigned short Bs[64][40];
    int tid = threadIdx.x;
    int lane = tid & 63, wv = tid >> 6;
    int q = lane >> 4, l15 = lane & 15;
    int Mbase = blockIdx.x * 64, Nbase = blockIdx.y * 64;
    int ldrow = tid >> 2, seg = tid & 3;
    const unsigned short* Ap = A + (size_t)(Mbase + ldrow) * 1024 + seg * 8;
    const unsigned short* Wp = W + (size_t)(Nbase + ldrow) * 1024 + seg * 8;
    f32x4 acc[4] = {};
    for (int k0 = 0; k0 < 1024; k0 += 32) {
        uint4 av = *(const uint4*)(Ap + k0);
        uint4 wvv = *(const uint4*)(Wp + k0);
        __syncthreads();
        *(uint4*)(&As[ldrow][seg * 8]) = av;
        *(uint4*)(&Bs[ldrow][seg * 8]) = wvv;
        __syncthreads();
        f16x8 af = *(const f16x8*)(&As[wv * 16 + l15][q * 8]);
#pragma unroll
        for (int nt = 0; nt < 4; nt++) {
            f16x8 bf = *(const f16x8*)(&Bs[nt * 16 + l15][q * 8]);
            acc[nt] = __builtin_amdgcn_mfma_f32_16x16x32_f16(af, bf, acc[nt], 0, 0, 0);
        }
    }
#pragma unroll
    for (int nt = 0; nt < 4; nt++) {
        int col = Nbase + nt * 16 + l15;
        float b = bias[col];
#pragma unroll
        for (int r = 0; r < 4; r++) {
            int row = Mbase + wv * 16 + q * 4 + r;
            float v = acc[nt][r] + b;
            v = v > 0.0f ? v : (__builtin_amdgcn_exp2f(1.4426950408889634f * v) - 1.0f);
            C[(size_t)row * 256 + col] = v;
        }
    }
}

// ---------- persistent recurrent kernel: 64 blocks x 512 thr, 16 rows/block ----------
// FULL Whh residency (r5-verified 47-reg/17-LDS split per wave) AND a 100% vmem-wait-free
// inner loop:
//   * acc starts from ZERO each step; x-proj is added AFTER the MFMAs from 16 packed-f16
//     registers (pure VALU, no per-step loads at all — r5 reloaded xpT every step and the
//     next step's first MFMA waited on those loads behind 8 stores in the vmcnt FIFO).
//   * out-stores issue at loop end and are NEVER waited: barrier is lgkm-only and no load
//     ever enters the vmcnt FIFO, so store retirement is fully asynchronous.
// Critical path/step: barrier -> ds_read af -> 64 MFMA -> elementwise -> ds_write -> barrier.
// Peak live set: wreg 188 + acc 32 + xph 16 + creg 8 + addr ~10 = 254 <= 256 (8 waves,
// launch_bounds(512,2), 156 KB LDS -> 1 block/CU, 2 waves/SIMD).
#define HB_STRIDE 264                    // fp16 elems per h row (33x16B)
#define HB_HALF   (16 * HB_STRIDE)      // one h buffer, elems
#define WLDS_OFF  (2 * HB_HALF * 2)     // bytes: 16896
#define WFRAGS    17                     // LDS weight frags per wave (1 KB each)
#define LSTM_LDS_BYTES (WLDS_OFF + 8 * WFRAGS * 1024)   // 156160 <= 163840

__global__ __launch_bounds__(512, 2) void lstm_rec(
    const unsigned short* __restrict__ Whh,   // [1024,256] fp16
    const float* __restrict__ xpT,            // [1024 gatecols, 1024 rows] fp32
    const float* __restrict__ h0,             // [1024,256]
    const float* __restrict__ c0,             // [1024,256]
    const int* __restrict__ seq_len,
    float* __restrict__ out)                  // [1024, T, 256]
{
    __shared__ uint4 smem4[LSTM_LDS_BYTES / 16];
    unsigned short* hbuf = (unsigned short*)smem4;           // [2][16][HB_STRIDE]
    unsigned char* wlds = (unsigned char*)smem4 + WLDS_OFF;  // 8 waves * 17 frags * 1 KB
    const int tid = threadIdx.x;
    const int lane = tid & 63, wv = tid >> 6;   // wv 0..7
    const int q = lane >> 4, l15 = lane & 15;
    const int T = *seq_len;
    const int rowbase = blockIdx.x * 16;

    {   // h0 -> hbuf[0] rows 0..15 as fp16 (512 thr * 8 elems = 16*256 exactly)
        int e = tid * 8;
        int r = e >> 8, cc = e & 255;
        const float* s = h0 + (size_t)(rowbase + r) * 256 + cc;
        float4 v0 = *(const float4*)s;
        float4 v1 = *(const float4*)(s + 4);
        unsigned short* d = hbuf + r * HB_STRIDE + cc;
        d[0] = f2h(v0.x); d[1] = f2h(v0.y); d[2] = f2h(v0.z); d[3] = f2h(v0.w);
        d[4] = f2h(v1.x); d[5] = f2h(v1.y); d[6] = f2h(v1.z); d[7] = f2h(v1.w);
    }

    // weight fragment (kt,g,ct): elem = g*65536 + wv*8192 + ct*4096 + l15*256 + kt*32 + q*8
    const unsigned short* wb = Whh + wv * 8192 + l15 * 256 + q * 8;

    // 47 frags -> registers (frag id fi = kt*8 + g*2 + ct, kt 0..5; fi==47 lives in LDS)
    uint4 wreg[47];
#pragma unroll
    for (int kt = 0; kt < 6; kt++)
#pragma unroll
        for (int g = 0; g < 4; g++)
#pragma unroll
            for (int ct = 0; ct < 2; ct++) {
                int fi = kt * 8 + g * 2 + ct;
                if (fi < 47)
                    wreg[fi] = *(const uint4*)(wb + (size_t)g * 65536 + ct * 4096 + kt * 32);
            }

    // 17 frags -> LDS: slots 0-7 = kt6, 8-15 = kt7, 16 = (kt5,g3,ct1); lane-linear 16B
    unsigned char* wlp = wlds + wv * (WFRAGS * 1024) + lane * 16;
#pragma unroll
    for (int fi = 0; fi < WFRAGS; fi++) {
        int kt = (fi < 8) ? 6 : (fi < 16 ? 7 : 5);
        int p  = (fi < 16) ? (fi & 7) : 7;
        int g = p >> 1, ct = p & 1;
        uint4 v = *(const uint4*)(wb + (size_t)g * 65536 + ct * 4096 + kt * 32);
        *(uint4*)(wlp + fi * 1024) = v;
    }

    // c0 -> 8 f32 regs
    float creg[8];
#pragma unroll
    for (int ct = 0; ct < 2; ct++)
#pragma unroll
        for (int r = 0; r < 4; r++)
            creg[ct * 4 + r] = c0[(size_t)(rowbase + q * 4 + r) * 256 + wv * 32 + ct * 16 + l15];

    // x-proj -> 16 packed-f16 regs (prologue only; per-step it's a VALU add after MFMA).
    // xph[2p + (r>>1)] lo/hi holds xp for (p, r): p = g*2+ct, gatecol = g*256+wv*32+ct*16+l15
    unsigned int xph[16];
    {
        const float* xpb = xpT + (size_t)(wv * 32 + l15) * 1024 + rowbase + (q << 2);
#pragma unroll
        for (int p = 0; p < 8; p++) {
            f32x4 v = *(const f32x4*)(xpb + (size_t)(p >> 1) * 262144 + (p & 1) * 16384);
            xph[p * 2]     = (unsigned int)f2h(v[0]) | ((unsigned int)f2h(v[1]) << 16);
            xph[p * 2 + 1] = (unsigned int)f2h(v[2]) | ((unsigned int)f2h(v[3]) << 16);
        }
    }

    float* outp = out + ((size_t)(rowbase + q * 4) * T) * 256 + wv * 32 + l15;

    __syncthreads();

    for (int t = 0; t < T; t++) {
        const unsigned short* hb = hbuf + (t & 1) * HB_HALF + l15 * HB_STRIDE + q * 8;
        // acc zero-init (x-proj is added after the MFMAs — no memory dependency anywhere)
        f32x4 acc[8];
#pragma unroll
        for (int p = 0; p < 8; p++) {
            acc[p][0] = 0.0f; acc[p][1] = 0.0f; acc[p][2] = 0.0f; acc[p][3] = 0.0f;
        }
        // K loop: all weights resident (regs or LDS); 1 af read feeds 8 MFMAs
#pragma unroll
        for (int kt = 0; kt < 8; kt++) {
            f16x8 af = *(const f16x8*)(hb + kt * 32);
#pragma unroll
            for (int p = 0; p < 8; p++) {
                f16x8 bf;
                if (kt < 6 && !(kt == 5 && p == 7))
                    bf = as_f16x8(wreg[kt * 8 + p]);
                else if (kt == 6)
                    bf = *(const f16x8*)(wlp + p * 1024);
                else if (kt == 7)
                    bf = *(const f16x8*)(wlp + (8 + p) * 1024);
                else // kt==5, p==7
                    bf = *(const f16x8*)(wlp + 16 * 1024);
                acc[p] = __builtin_amdgcn_mfma_f32_16x16x32_f16(af, bf, acc[p], 0, 0, 0);
            }
        }
        // elementwise: gate = acc + xp (unpacked from regs), then LSTM cell (pure VALU)
        float hv[8];
#pragma unroll
        for (int ct = 0; ct < 2; ct++)
#pragma unroll
            for (int r = 0; r < 4; r++) {
                int w = r >> 1;
                float xi = (r & 1) ? h2f_hi(xph[(0 + ct) * 2 + w]) : h2f_lo(xph[(0 + ct) * 2 + w]);
                float xf = (r & 1) ? h2f_hi(xph[(2 + ct) * 2 + w]) : h2f_lo(xph[(2 + ct) * 2 + w]);
                float xg = (r & 1) ? h2f_hi(xph[(4 + ct) * 2 + w]) : h2f_lo(xph[(4 + ct) * 2 + w]);
                float xo = (r & 1) ? h2f_hi(xph[(6 + ct) * 2 + w]) : h2f_lo(xph[(6 + ct) * 2 + w]);
                float ig = sigmoid_fast(acc[0 + ct][r] + xi);
                float fg = sigmoid_fast(acc[2 + ct][r] + xf);
                float gg = tanh_fast(acc[4 + ct][r] + xg);
                float og = sigmoid_fast(acc[6 + ct][r] + xo);
                float cn = fg * creg[ct * 4 + r] + ig * gg;
                creg[ct * 4 + r] = cn;
                hv[ct * 4 + r] = og * tanh_fast(cn);
            }
        // write next h (LDS) first, then ys (global; retires async — never waited)
        unsigned short* hn = hbuf + ((t + 1) & 1) * HB_HALF + (q * 4) * HB_STRIDE + wv * 32 + l15;
#pragma unroll
        for (int ct = 0; ct < 2; ct++)
#pragma unroll
            for (int r = 0; r < 4; r++)
                hn[r * HB_STRIDE + ct * 16] = f2h(hv[ct * 4 + r]);
#pragma unroll
        for (int ct = 0; ct < 2; ct++)
#pragma unroll
            for (int r = 0; r < 4; r++)
                outp[(size_t)r * T * 256 + ct * 16] = hv[ct * 4 + r];
        outp += 256;
        lds_barrier();
    }
}

extern "C" void kernel_launch(void* const* d_in, const int* in_sizes, int n_in,
                              void* d_out, int out_size, void* d_ws, size_t ws_size,
                              hipStream_t stream) {
    const float* h   = (const float*)d_in[0];
    const float* c   = (const float*)d_in[1];
    const int*   seqp= (const int*)d_in[2];
    const float* iWh = (const float*)d_in[3];
    const float* ibh = (const float*)d_in[4];
    const float* iWc = (const float*)d_in[5];
    const float* ibc = (const float*)d_in[6];
    const float* Wih = (const float*)d_in[7];
    const float* Whh = (const float*)d_in[8];
    const float* bih = (const float*)d_in[9];
    const float* bhh = (const float*)d_in[10];
    float* out = (float*)d_out;
    unsigned char* ws = (unsigned char*)d_ws;

    // workspace layout (16B-aligned)
    unsigned short* hc_h  = (unsigned short*)(ws + 0);        // [1024,1024] fp16 = 2 MB
    unsigned short* iWh_h = (unsigned short*)(ws + 2097152);  // [256,1024]
    unsigned short* iWc_h = (unsigned short*)(ws + 2621440);  // [256,1024]
    unsigned short* Wih_h = (unsigned short*)(ws + 3145728);  // [1024,512]
    unsigned short* Whh_h = (unsigned short*)(ws + 4194304);  // [1024,256]
    float* h0  = (float*)(ws + 4718592);                       // [1024,256]
    float* c0  = (float*)(ws + 5767168);                       // [1024,256]
    float* xpT = (float*)(ws + 6815744);                       // [1024 gatecols,1024 rows]

    // fp16 conversions: all 6 tensors in one dispatch
    convert_all<<<2304, 256, 0, stream>>>(h, c, iWh, iWc, Wih, Whh,
                                          hc_h, iWh_h, iWc_h, Wih_h, Whh_h);

    // init states (fused pair) + transposed x_proj:
    // xpT[gatecol, batch] = Wih[gatecol,:] . h[batch,:] + bih[gatecol] + bhh[gatecol]
    gemm_init<<<dim3(16, 4, 2), 256, 0, stream>>>(hc_h, iWh_h, iWc_h, h0, c0, ibh, ibc);
    gemm_bt<<<dim3(16, 16), 256, 0, stream>>>(Wih_h, hc_h, xpT, bih, bhh,
                                              512, 512, 1024, 1024, 0, 1);

    // recurrence: 64 blocks x 512 threads, fully weight-resident, vmem-wait-free loop
    lstm_rec<<<64, 512, 0, stream>>>(Whh_h, xpT, h0, c0, seqp, out);
}